// Round 6
// baseline (1108.401 us; speedup 1.0000x reference)
//
#include <hip/hip_runtime.h>
#include <math.h>

#define C 28   // channels == dim_head == rank
#define N 64   // tokens per window

// LDS float offsets (regions overlaid in time; see phase comments)
#define QT_OFF    0      // [28][64]  phase A -> sim
#define KT_OFF    1792   // [28][64]  phase A -> sim
#define AT_OFF    1536   // [32][64]  swizzled A^T chunk (after sim dead)
#define THP_OFF   0      // [16][65]  theta partials (overlays QT after sim; barrier!)
#define MAXP_OFF  1792   // [16][65]  max partials (overlays KT after sim; barrier!)
#define ZP_OFF    0      // [16][65]  Z partials (after THP dead)
#define V_OFF     3584   // [64][28]  phase A -> AV
#define OT_OFF    3584   // [64][28]  overlays V after AV
#define SQ_OFF    5376
#define SGK_OFF   5440
#define MR_OFF    5504   // row max
#define Z_OFF     5568
#define TH_OFF    5632
#define SQP_OFF   5504   // wave1 sig_q partial (overlays MR, phase A only)
#define SGKP_OFF  5568   // wave1 sig_k partial (overlays Z, phase A only)
#define THETA_OFF 5696
#define LDS_FLOATS 5760  // 23040 B -> 7 blocks/CU x 2 waves = 14 waves/CU

__global__ __launch_bounds__(128, 4)
void fa_tiled2(const float* __restrict__ x,
               const float* __restrict__ Wqk,   // [56][28]
               const float* __restrict__ Wv,    // [28][28]
               const float* __restrict__ Wout,  // [28][28]
               const float* __restrict__ bout,  // [28]
               const float* __restrict__ Wpcq,  // [28]
               const float* __restrict__ bpcq,  // [1]
               const float* __restrict__ Wpck,  // [28]
               const float* __restrict__ bpck,  // [1]
               const float* __restrict__ Wm1,   // [64]
               const float* __restrict__ Wm2a,  // [64][64]
               const float* __restrict__ Wm2b,  // [64]
               float* __restrict__ out)
{
    __shared__ float S[LDS_FLOATS];

    const int tid = threadIdx.x;       // 0..127 (2 waves per problem)
    const int w   = tid >> 6;          // wave id 0/1
    const int ln  = tid & 63;
    const int pid = blockIdx.x;        // 0..8191
    const int win = pid >> 3;
    const int Bi  = pid & 7;
    const int hw = win >> 5, ww = win & 31;
    const int b0 = ln >> 3, b1 = ln & 7;
    const size_t base = ((((size_t)Bi * 256) + (size_t)(hw * 8 + b0)) * 256
                         + (size_t)(ww * 8 + b1)) * C;

    // ============ Phase A: projections, d-split across the 2 waves ============
    float xr[C];
    {
        const float4* p = (const float4*)(x + base);
        #pragma unroll
        for (int i = 0; i < 7; ++i) {
            float4 t = p[i];
            xr[4*i+0] = t.x; xr[4*i+1] = t.y; xr[4*i+2] = t.z; xr[4*i+3] = t.w;
        }
    }

    const int d4lo = w ? 4 : 0;
    const int d4hi = w ? 7 : 4;
    float sqp_reg = 0.f, sgp_reg = 0.f;

    // q -> QT (transposed); sig_q partial
    {
        float sqp = 0.f;
        #pragma unroll 2
        for (int d4 = d4lo; d4 < d4hi; ++d4) {
            float qq[4];
            #pragma unroll
            for (int t = 0; t < 4; ++t) {
                const int d = 4*d4 + t;
                float a0 = 0.f, a1 = 0.f;
                #pragma unroll
                for (int c = 0; c < C; c += 2) {
                    a0 += Wqk[d*C + c]     * xr[c];
                    a1 += Wqk[d*C + c + 1] * xr[c+1];
                }
                qq[t] = a0 + a1;
                S[QT_OFF + d*64 + ln] = qq[t];
            }
            sqp += qq[0] * Wpcq[4*d4+0];
            sqp += qq[1] * Wpcq[4*d4+1];
            sqp += qq[2] * Wpcq[4*d4+2];
            sqp += qq[3] * Wpcq[4*d4+3];
        }
        if (w) S[SQP_OFF + ln] = sqp; else sqp_reg = sqp;
    }

    // k -> KT (transposed), v -> V (row-major float4); sig_k partial
    {
        float sgp = 0.f;
        #pragma unroll 2
        for (int d4 = d4lo; d4 < d4hi; ++d4) {
            float kk[4], vv[4];
            #pragma unroll
            for (int t = 0; t < 4; ++t) {
                const int d = 4*d4 + t;
                float k0 = 0.f, k1 = 0.f, v0 = 0.f, v1 = 0.f;
                #pragma unroll
                for (int c = 0; c < C; c += 2) {
                    k0 += Wqk[(C+d)*C + c]     * xr[c];
                    k1 += Wqk[(C+d)*C + c + 1] * xr[c+1];
                    v0 += Wv[d*C + c]          * xr[c];
                    v1 += Wv[d*C + c + 1]      * xr[c+1];
                }
                kk[t] = k0 + k1;
                vv[t] = v0 + v1;
                S[KT_OFF + d*64 + ln] = kk[t];
            }
            sgp += kk[0] * Wpck[4*d4+0];
            sgp += kk[1] * Wpck[4*d4+1];
            sgp += kk[2] * Wpck[4*d4+2];
            sgp += kk[3] * Wpck[4*d4+3];
            *(float4*)&S[V_OFF + ln*C + 4*d4] = make_float4(vv[0], vv[1], vv[2], vv[3]);
        }
        if (w) S[SGKP_OFF + ln] = sgp; else sgp_reg = sgp;
    }
    __syncthreads();
    if (w == 0) {
        S[SQ_OFF + ln]  = sqp_reg + S[SQP_OFF + ln]  + bpcq[0];
        S[SGK_OFF + ln] = sgp_reg + S[SGKP_OFF + ln] + bpck[0];
    }
    __syncthreads();

    // ============ sim: 8x4 register tile per lane over 128 lanes ============
    const int ti  = tid >> 4;    // 0..7: rows 8ti..8ti+7 (wave0: 0..3, wave1: 4..7)
    const int tjc = tid & 15;    // cols 4tjc..4tjc+3
    float acc[4][8];             // acc[cc][rr] = sraw[8ti+rr][4tjc+cc]
    #pragma unroll
    for (int cc = 0; cc < 4; ++cc)
        #pragma unroll
        for (int rr = 0; rr < 8; ++rr) acc[cc][rr] = 0.f;

    #pragma unroll 2
    for (int d = 0; d < C; ++d) {
        float4 qa = *(const float4*)&S[QT_OFF + d*64 + 8*ti];
        float4 qb = *(const float4*)&S[QT_OFF + d*64 + 8*ti + 4];
        float4 kv = *(const float4*)&S[KT_OFF + d*64 + 4*tjc];
        float q8[8] = {qa.x,qa.y,qa.z,qa.w,qb.x,qb.y,qb.z,qb.w};
        float k4[4] = {kv.x,kv.y,kv.z,kv.w};
        #pragma unroll
        for (int cc = 0; cc < 4; ++cc)
            #pragma unroll
            for (int rr = 0; rr < 8; ++rr)
                acc[cc][rr] += q8[rr] * k4[cc];
    }
    // CRITICAL: both waves must finish reading QT/KT before THP/MAXP overlay them
    __syncthreads();

    // theta partials (raw sim, diagonal excluded) -> THP (overlays QT, now safe)
    {
        float4 w4 = *(const float4*)&Wm1[4*tjc];
        float wm[4] = {w4.x, w4.y, w4.z, w4.w};
        #pragma unroll
        for (int rr = 0; rr < 8; ++rr) {
            float s = 0.f;
            #pragma unroll
            for (int cc = 0; cc < 4; ++cc) {
                float term = acc[cc][rr] * wm[cc];
                s += (4*tjc + cc == 8*ti + rr) ? 0.f : term;
            }
            S[THP_OFF + tjc*65 + 8*ti + rr] = s;
        }
    }

    // Sigma scale: (sraw*sq)*sgk
    {
        float4 a = *(const float4*)&S[SQ_OFF + 8*ti];
        float4 b = *(const float4*)&S[SQ_OFF + 8*ti + 4];
        float sq8[8] = {a.x,a.y,a.z,a.w,b.x,b.y,b.z,b.w};
        float4 g = *(const float4*)&S[SGK_OFF + 4*tjc];
        float sg4[4] = {g.x,g.y,g.z,g.w};
        #pragma unroll
        for (int cc = 0; cc < 4; ++cc)
            #pragma unroll
            for (int rr = 0; rr < 8; ++rr)
                acc[cc][rr] = (acc[cc][rr] * sq8[rr]) * sg4[cc];
    }

    // max partials -> MAXP (overlays KT, safe after the barrier above)
    #pragma unroll
    for (int rr = 0; rr < 8; ++rr) {
        float mp = fmaxf(fmaxf(acc[0][rr], acc[1][rr]), fmaxf(acc[2][rr], acc[3][rr]));
        S[MAXP_OFF + tjc*65 + 8*ti + rr] = mp;
    }
    __syncthreads();

    // reduces: wave0 -> theta row sums + MLP2 + theta scalar; wave1 -> row max
    if (w == 0) {
        float th = 0.f;
        #pragma unroll
        for (int t = 0; t < 16; ++t) th += S[THP_OFF + t*65 + ln];
        S[TH_OFF + ln] = th;
        // MLP2 (within-wave visibility of TH via lgkmcnt; no barrier needed)
        const float* wrow = Wm2a + ln * N;
        float a0 = 0.f, a1 = 0.f, a2 = 0.f, a3 = 0.f;
        #pragma unroll 4
        for (int i4 = 0; i4 < 16; ++i4) {
            float4 t4 = *(const float4*)&S[TH_OFF + 4*i4];
            float4 w4 = *(const float4*)&wrow[4*i4];
            a0 += t4.x*w4.x; a1 += t4.y*w4.y; a2 += t4.z*w4.z; a3 += t4.w*w4.w;
        }
        float t = (a0 + a1) + (a2 + a3);
        t = (t >= 0.f) ? t : 0.1f * t;
        float th_s = t * Wm2b[ln];
        #pragma unroll
        for (int off = 32; off > 0; off >>= 1)
            th_s += __shfl_xor(th_s, off, 64);
        if (ln == 0) S[THETA_OFF] = th_s;
    } else {
        float mv = -1e30f;
        #pragma unroll
        for (int t = 0; t < 16; ++t) mv = fmaxf(mv, S[MAXP_OFF + t*65 + ln]);
        S[MR_OFF + ln] = mv;
    }
    __syncthreads();

    const float theta = S[THETA_OFF];

    // exp + Z partials + mask; write AT chunk0 (cols 0..31, lanes tjc<8)
    {
        float4 a = *(const float4*)&S[MR_OFF + 8*ti];
        float4 b = *(const float4*)&S[MR_OFF + 8*ti + 4];
        float m8[8] = {a.x,a.y,a.z,a.w,b.x,b.y,b.z,b.w};
        #pragma unroll
        for (int rr = 0; rr < 8; ++rr) {
            float zp = 0.f;
            #pragma unroll
            for (int cc = 0; cc < 4; ++cc) {
                float ss = acc[cc][rr];
                float e = __expf(ss - m8[rr]);
                zp += e;
                acc[cc][rr] = (ss > theta) ? e : 0.f;
            }
            S[ZP_OFF + tjc*65 + 8*ti + rr] = zp;
        }
    }
    if (tjc < 8) {
        #pragma unroll
        for (int cc = 0; cc < 4; ++cc) {
            const int jc = 4*tjc + cc;
            const int K  = (jc + (jc >> 3)) & 7;
            const int c0 = 2*ti, c1 = 2*ti + 1;
            const int pc0 = (c0 & 8) | ((c0 + K) & 7);
            const int pc1 = (c1 & 8) | ((c1 + K) & 7);
            *(float4*)&S[AT_OFF + jc*64 + pc0*4] = make_float4(acc[cc][0], acc[cc][1], acc[cc][2], acc[cc][3]);
            *(float4*)&S[AT_OFF + jc*64 + pc1*4] = make_float4(acc[cc][4], acc[cc][5], acc[cc][6], acc[cc][7]);
        }
    }
    __syncthreads();

    // Z row sums (wave0) concurrent with AV chunk0 start
    if (w == 0) {
        float z = 0.f;
        #pragma unroll
        for (int t = 0; t < 16; ++t) z += S[ZP_OFF + t*65 + ln];
        S[Z_OFF + ln] = z;
    }

    // ============ AV: d-split across waves; two j-chunks through AT ============
    const int tio = ln >> 3;                 // output rows 8tio..8tio+7
    const int dgx = ln & 7;
    const int dgp = 8*w + dgx;               // d-pair index, valid < 14
    const int dgpc = (dgp < 14) ? dgp : 12;
    float av[8][2];
    #pragma unroll
    for (int rr = 0; rr < 8; ++rr) { av[rr][0] = 0.f; av[rr][1] = 0.f; }

    #pragma unroll 4
    for (int j = 0; j < 32; ++j) {
        const int jc = j;
        const int K  = (jc + (jc >> 3)) & 7;
        const int c0 = 2*tio, c1 = 2*tio + 1;
        const int pc0 = (c0 & 8) | ((c0 + K) & 7);
        const int pc1 = (c1 & 8) | ((c1 + K) & 7);
        float4 aa = *(const float4*)&S[AT_OFF + jc*64 + pc0*4];
        float4 ab = *(const float4*)&S[AT_OFF + jc*64 + pc1*4];
        float2 vv = *(const float2*)&S[V_OFF + j*C + 2*dgpc];
        float a8[8] = {aa.x,aa.y,aa.z,aa.w,ab.x,ab.y,ab.z,ab.w};
        #pragma unroll
        for (int rr = 0; rr < 8; ++rr) {
            av[rr][0] += a8[rr] * vv.x;
            av[rr][1] += a8[rr] * vv.y;
        }
    }
    __syncthreads();   // chunk0 consumed
    if (tjc >= 8) {
        #pragma unroll
        for (int cc = 0; cc < 4; ++cc) {
            const int jc = 4*(tjc - 8) + cc;
            const int K  = (jc + (jc >> 3)) & 7;
            const int c0 = 2*ti, c1 = 2*ti + 1;
            const int pc0 = (c0 & 8) | ((c0 + K) & 7);
            const int pc1 = (c1 & 8) | ((c1 + K) & 7);
            *(float4*)&S[AT_OFF + jc*64 + pc0*4] = make_float4(acc[cc][0], acc[cc][1], acc[cc][2], acc[cc][3]);
            *(float4*)&S[AT_OFF + jc*64 + pc1*4] = make_float4(acc[cc][4], acc[cc][5], acc[cc][6], acc[cc][7]);
        }
    }
    __syncthreads();
    #pragma unroll 4
    for (int j = 32; j < 64; ++j) {
        const int jc = j - 32;
        const int K  = (jc + (jc >> 3)) & 7;
        const int c0 = 2*tio, c1 = 2*tio + 1;
        const int pc0 = (c0 & 8) | ((c0 + K) & 7);
        const int pc1 = (c1 & 8) | ((c1 + K) & 7);
        float4 aa = *(const float4*)&S[AT_OFF + jc*64 + pc0*4];
        float4 ab = *(const float4*)&S[AT_OFF + jc*64 + pc1*4];
        float2 vv = *(const float2*)&S[V_OFF + j*C + 2*dgpc];
        float a8[8] = {aa.x,aa.y,aa.z,aa.w,ab.x,ab.y,ab.z,ab.w};
        #pragma unroll
        for (int rr = 0; rr < 8; ++rr) {
            av[rr][0] += a8[rr] * vv.x;
            av[rr][1] += a8[rr] * vv.y;
        }
    }
    __syncthreads();   // all V reads done before OT overlays V

    // normalize by Z and write OT
    {
        float4 za = *(const float4*)&S[Z_OFF + 8*tio];
        float4 zb = *(const float4*)&S[Z_OFF + 8*tio + 4];
        float z8[8] = {za.x,za.y,za.z,za.w,zb.x,zb.y,zb.z,zb.w};
        #pragma unroll
        for (int rr = 0; rr < 8; ++rr) {
            float rz = 1.0f / z8[rr];
            av[rr][0] *= rz; av[rr][1] *= rz;
        }
    }
    if (dgp < 14) {
        #pragma unroll
        for (int rr = 0; rr < 8; ++rr)
            *(float2*)&S[OT_OFF + (8*tio + rr)*C + 2*dgp] = make_float2(av[rr][0], av[rr][1]);
    }
    __syncthreads();

    // ============ epilogue: out projection, e-split across waves ============
    float o[C];
    #pragma unroll
    for (int i = 0; i < 7; ++i) {
        float4 t = *(const float4*)&S[OT_OFF + ln*C + 4*i];
        o[4*i+0] = t.x; o[4*i+1] = t.y; o[4*i+2] = t.z; o[4*i+3] = t.w;
    }
    {
        float4* yp = (float4*)(out + base);
        const int e4lo = w ? 4 : 0;
        const int e4hi = w ? 7 : 4;
        #pragma unroll 2
        for (int e4 = e4lo; e4 < e4hi; ++e4) {
            float yy[4];
            #pragma unroll
            for (int t = 0; t < 4; ++t) {
                const int e = 4*e4 + t;
                float a0 = 0.f, a1 = 0.f;
                #pragma unroll
                for (int d = 0; d < C; d += 2) {
                    a0 += Wout[e*C + d]     * o[d];
                    a1 += Wout[e*C + d + 1] * o[d+1];
                }
                yy[t] = (a0 + a1) + bout[e];
            }
            yp[e4] = make_float4(yy[0], yy[1], yy[2], yy[3]);
        }
    }
}

extern "C" void kernel_launch(void* const* d_in, const int* in_sizes, int n_in,
                              void* d_out, int out_size, void* d_ws, size_t ws_size,
                              hipStream_t stream) {
    const float* x     = (const float*)d_in[0];
    const float* W_qk  = (const float*)d_in[1];
    const float* W_v   = (const float*)d_in[2];
    const float* W_out = (const float*)d_in[3];
    const float* b_out = (const float*)d_in[4];
    const float* W_pcq = (const float*)d_in[5];
    const float* b_pcq = (const float*)d_in[6];
    const float* W_pck = (const float*)d_in[7];
    const float* b_pck = (const float*)d_in[8];
    const float* W_m1  = (const float*)d_in[9];
    const float* W_m2a = (const float*)d_in[10];
    const float* W_m2b = (const float*)d_in[11];
    float* y = (float*)d_out;

    // 8192 problems, one 128-thread (2-wave) block per problem
    hipLaunchKernelGGL(fa_tiled2, dim3(8192), dim3(128), 0, stream,
                       x, W_qk, W_v, W_out, b_out, W_pcq, b_pcq,
                       W_pck, b_pck, W_m1, W_m2a, W_m2b, y);
}